// Round 7
// baseline (645.324 us; speedup 1.0000x reference)
//
#include <hip/hip_runtime.h>
#include <hip/hip_bf16.h>

typedef unsigned short u16;
typedef unsigned int u32;

using bf16x8 = __attribute__((ext_vector_type(8))) short;
using f32x4  = __attribute__((ext_vector_type(4))) float;

#define MFMA16(a, b, c) __builtin_amdgcn_mfma_f32_16x16x32_bf16((a), (b), (c), 0, 0, 0)

__device__ __forceinline__ u16 f2bf(float f) {
    u32 u = __builtin_bit_cast(u32, f);
    u = (u + 0x7fffu + ((u >> 16) & 1u)) >> 16;
    return (u16)u;
}

// ---------------------------------------------------------------------------
// Prep kernel (unchanged, proven): weight cvt + K/V projection.
// ---------------------------------------------------------------------------
__global__ __launch_bounds__(256, 2) void frgca_prep(
    const float* __restrict__ region,
    const float* __restrict__ in_w,
    const float* __restrict__ in_b,
    const float* __restrict__ out_w,
    u16* __restrict__ wq, u16* __restrict__ wo,
    u16* __restrict__ kt, u16* __restrict__ vt)
{
    __shared__ u16 As2[64 * 520];
    const int tid = threadIdx.x;
    const int bid = blockIdx.x;

    if (bid < 32) {
        const float4* w4q = (const float4*)in_w;
        const float4* w4o = (const float4*)out_w;
        int t = bid * 256 + tid;
#pragma unroll
        for (int i = 0; i < 16; ++i) {
            int idx = t + i * 8192;
            float4 v;
            u16* dst;
            if (idx < 65536) { v = w4q[idx]; dst = wq + idx * 4; }
            else             { v = w4o[idx - 65536]; dst = wo + (idx - 65536) * 4; }
            ushort4 o;
            o.x = f2bf(v.x); o.y = f2bf(v.y); o.z = f2bf(v.z); o.w = f2bf(v.w);
            *(ushort4*)dst = o;
        }
        return;
    }

    const int t2 = bid - 32;
    const int b  = t2 >> 2;
    const int nc = t2 & 3;

    {
        const float4* r4 = (const float4*)(region + (size_t)b * 64 * 512);
#pragma unroll
        for (int i = 0; i < 32; ++i) {
            int f4  = tid + i * 256;
            int row = f4 >> 7;
            int c4  = f4 & 127;
            float4 v = r4[f4];
            ushort4 o;
            o.x = f2bf(v.x); o.y = f2bf(v.y); o.z = f2bf(v.z); o.w = f2bf(v.w);
            *(ushort4*)&As2[row * 520 + c4 * 4] = o;
        }
    }
    __syncthreads();

    const int lane = tid & 63, w = tid >> 6;
    const int lo16 = lane & 15, g = lane >> 4;
    const int e0 = nc * 256 + w * 64;

    f32x4 acc[4][4];
#pragma unroll
    for (int mt = 0; mt < 4; ++mt)
#pragma unroll
        for (int nt = 0; nt < 4; ++nt)
            acc[mt][nt] = f32x4{0.f, 0.f, 0.f, 0.f};

    const float* w2 = in_w + 512 * 512;

#pragma unroll 2
    for (int ks = 0; ks < 16; ++ks) {
        const int kc = ks * 32 + 8 * g;
        bf16x8 a[4], bb[4];
#pragma unroll
        for (int mt = 0; mt < 4; ++mt)
            a[mt] = *(const bf16x8*)&As2[(mt * 16 + lo16) * 520 + kc];
#pragma unroll
        for (int nt = 0; nt < 4; ++nt) {
            const int e = e0 + nt * 16 + lo16;
            const float* src = w2 + (size_t)e * 512 + kc;
            float4 v0 = *(const float4*)src;
            float4 v1 = *(const float4*)(src + 4);
            bf16x8 bv;
            bv[0] = (short)f2bf(v0.x); bv[1] = (short)f2bf(v0.y);
            bv[2] = (short)f2bf(v0.z); bv[3] = (short)f2bf(v0.w);
            bv[4] = (short)f2bf(v1.x); bv[5] = (short)f2bf(v1.y);
            bv[6] = (short)f2bf(v1.z); bv[7] = (short)f2bf(v1.w);
            bb[nt] = bv;
        }
#pragma unroll
        for (int mt = 0; mt < 4; ++mt)
#pragma unroll
            for (int nt = 0; nt < 4; ++nt)
                acc[mt][nt] = MFMA16(a[mt], bb[nt], acc[mt][nt]);
    }

#pragma unroll
    for (int nt = 0; nt < 4; ++nt) {
        const int e = e0 + nt * 16 + lo16;
        const float bias = in_b[512 + e];
#pragma unroll
        for (int mt = 0; mt < 4; ++mt)
#pragma unroll
            for (int i = 0; i < 4; ++i) {
                const int r = mt * 16 + 4 * g + i;
                const u16 o = f2bf(acc[mt][nt][i] + bias);
                if (e < 512) {
                    const int h = e >> 6, d = e & 63;
                    kt[(((size_t)(b * 8 + h)) * 64 + r) * 64 + d] = o;
                } else {
                    const int e2 = e - 512;
                    const int h = e2 >> 6, d = e2 & 63;
                    vt[(((size_t)(b * 8 + h)) * 64 + d) * 64 + r] = o;
                }
            }
    }
}

// ---------------------------------------------------------------------------
// Kernel A (R7): fused Q-proj + attention (R6-proven), with the final cb
// store upgraded: per-wave LDS roundtrip in the free 8KB Qw slice + 16B
// coalesced global stores.  LDS total 80KB (proven launchable).
// ---------------------------------------------------------------------------
__global__ __launch_bounds__(512, 4) void frgca_qattn(
    const float* __restrict__ visual,
    const float* __restrict__ mask,
    const float* __restrict__ in_b,
    const u16* __restrict__ wq,
    const u16* __restrict__ kt, const u16* __restrict__ vt,
    u16* __restrict__ cb)
{
    __shared__ char regA[65536];
    __shared__ float Ms[4096];

    const int tid = threadIdx.x;
    const int w = tid >> 6, lane = tid & 63;
    const int lo16 = lane & 15, g = lane >> 4;
    const int xr = (lo16 & 7) << 4;
    const int pt = blockIdx.x, b = blockIdx.y;
    const int P0 = pt * 64;
    const size_t vbase = ((size_t)(b * 4096 + P0)) * 512;

    {
        const float4* v4 = (const float4*)(visual + vbase);
#pragma unroll
        for (int i = 0; i < 16; ++i) {
            int f4  = tid + i * 512;
            int row = f4 >> 7, c4 = f4 & 127;
            float4 v = v4[f4];
            ushort4 o;
            o.x = f2bf(v.x); o.y = f2bf(v.y); o.z = f2bf(v.z); o.w = f2bf(v.w);
            *(ushort4*)(regA + row * 1024 + ((c4 * 8) ^ ((row & 7) << 4))) = o;
        }
        const float4* m4 = (const float4*)(mask + ((size_t)(b * 4096 + P0)) * 64);
#pragma unroll
        for (int i = 0; i < 2; ++i) {
            int f4 = tid + i * 512;
            int p = f4 >> 4, r0 = (f4 & 15) * 4;
            float4 v = m4[f4];
            int pb = p * 64, px = p & 31;
            Ms[pb + ((r0 + 0) ^ px)] = (1.0f - v.x) * -1e9f;
            Ms[pb + ((r0 + 1) ^ px)] = (1.0f - v.y) * -1e9f;
            Ms[pb + ((r0 + 2) ^ px)] = (1.0f - v.z) * -1e9f;
            Ms[pb + ((r0 + 3) ^ px)] = (1.0f - v.w) * -1e9f;
        }
    }
    __syncthreads();

    const int e0 = w * 64;

    // ---- P1: Q = visual @ Wq^T + bq (R2/R6 verbatim) ----
    f32x4 acc[4][4];
#pragma unroll
    for (int mt = 0; mt < 4; ++mt)
#pragma unroll
        for (int nt = 0; nt < 4; ++nt)
            acc[mt][nt] = f32x4{0.f, 0.f, 0.f, 0.f};

    const u16* wqR0 = wq + ((size_t)(e0 + 0 * 16 + lo16)) * 512;
    const u16* wqR1 = wq + ((size_t)(e0 + 1 * 16 + lo16)) * 512;
    const u16* wqR2 = wq + ((size_t)(e0 + 2 * 16 + lo16)) * 512;
    const u16* wqR3 = wq + ((size_t)(e0 + 3 * 16 + lo16)) * 512;
    bf16x8 nb0 = *(const bf16x8*)&wqR0[8 * g];
    bf16x8 nb1 = *(const bf16x8*)&wqR1[8 * g];
    bf16x8 nb2 = *(const bf16x8*)&wqR2[8 * g];
    bf16x8 nb3 = *(const bf16x8*)&wqR3[8 * g];

#pragma unroll
    for (int ks = 0; ks < 16; ++ks) {
        const int kc = ks * 32 + 8 * g;
        bf16x8 cb0 = nb0, cb1 = nb1, cb2 = nb2, cb3 = nb3;
        if (ks < 15) {
            const int kn = kc + 32;
            nb0 = *(const bf16x8*)&wqR0[kn];
            nb1 = *(const bf16x8*)&wqR1[kn];
            nb2 = *(const bf16x8*)&wqR2[kn];
            nb3 = *(const bf16x8*)&wqR3[kn];
        }
        bf16x8 a[4];
#pragma unroll
        for (int mt = 0; mt < 4; ++mt)
            a[mt] = *(const bf16x8*)(regA + (mt * 16 + lo16) * 1024 + ((kc * 2) ^ xr));
#pragma unroll
        for (int mt = 0; mt < 4; ++mt) {
            acc[mt][0] = MFMA16(a[mt], cb0, acc[mt][0]);
            acc[mt][1] = MFMA16(a[mt], cb1, acc[mt][1]);
            acc[mt][2] = MFMA16(a[mt], cb2, acc[mt][2]);
            acc[mt][3] = MFMA16(a[mt], cb3, acc[mt][3]);
        }
    }

    const u16* KtH = kt + ((size_t)(b * 8 + w)) * 4096;
    bf16x8 ak[4][2];
#pragma unroll
    for (int ks2 = 0; ks2 < 2; ++ks2)
#pragma unroll
        for (int mt = 0; mt < 4; ++mt)
            ak[mt][ks2] = *(const bf16x8*)&KtH[(mt * 16 + lo16) * 64 + ks2 * 32 + 8 * g];

#pragma unroll
    for (int nt = 0; nt < 4; ++nt) {
        const float bq = in_b[e0 + nt * 16 + lo16];
#pragma unroll
        for (int mt = 0; mt < 4; ++mt)
#pragma unroll
            for (int i = 0; i < 4; ++i)
                acc[mt][nt][i] += bq;
    }
    __syncthreads();

    char* Qw = regA + w * 8192;
#pragma unroll
    for (int mt = 0; mt < 4; ++mt)
#pragma unroll
        for (int nt = 0; nt < 4; ++nt)
#pragma unroll
            for (int i = 0; i < 4; ++i) {
                const int p = mt * 16 + 4 * g + i;
                const int d = nt * 16 + lo16;
                *(u16*)(Qw + p * 128 + ((d * 2) ^ ((p & 7) << 4))) = f2bf(acc[mt][nt][i]);
            }

    // ---- P2: S^T = K @ Q^T (verbatim) ----
    f32x4 s[4][4];
#pragma unroll
    for (int mt = 0; mt < 4; ++mt)
#pragma unroll
        for (int nt = 0; nt < 4; ++nt)
            s[mt][nt] = f32x4{0.f, 0.f, 0.f, 0.f};

#pragma unroll
    for (int ks2 = 0; ks2 < 2; ++ks2) {
        const int kcb = (ks2 * 32 + 8 * g) * 2;
        bf16x8 bq_[4];
#pragma unroll
        for (int nt = 0; nt < 4; ++nt)
            bq_[nt] = *(const bf16x8*)(Qw + (nt * 16 + lo16) * 128 + (kcb ^ xr));
#pragma unroll
        for (int mt = 0; mt < 4; ++mt)
#pragma unroll
            for (int nt = 0; nt < 4; ++nt)
                s[mt][nt] = MFMA16(ak[mt][ks2], bq_[nt], s[mt][nt]);
    }

    const u16* VtH = vt + ((size_t)(b * 8 + w)) * 4096;
    bf16x8 av[4][2];
#pragma unroll
    for (int ks2 = 0; ks2 < 2; ++ks2)
#pragma unroll
        for (int mt = 0; mt < 4; ++mt)
            av[mt][ks2] = *(const bf16x8*)&VtH[(mt * 16 + lo16) * 64 + ks2 * 32 + 8 * g];

    // ---- softmax (verbatim) ----
#pragma unroll
    for (int nt = 0; nt < 4; ++nt) {
        const int p = nt * 16 + lo16;
        const int pb = p * 64, px = p & 31;
        float mx = -3.4e38f;
#pragma unroll
        for (int mt = 0; mt < 4; ++mt)
#pragma unroll
            for (int i = 0; i < 4; ++i) {
                float v = s[mt][nt][i] * 0.125f + Ms[pb + ((mt * 16 + 4 * g + i) ^ px)];
                s[mt][nt][i] = v;
                mx = fmaxf(mx, v);
            }
        mx = fmaxf(mx, __shfl_xor(mx, 16));
        mx = fmaxf(mx, __shfl_xor(mx, 32));
        float sum = 0.f;
#pragma unroll
        for (int mt = 0; mt < 4; ++mt)
#pragma unroll
            for (int i = 0; i < 4; ++i) {
                float ev = __expf(s[mt][nt][i] - mx);
                s[mt][nt][i] = ev;
                sum += ev;
            }
        sum += __shfl_xor(sum, 16);
        sum += __shfl_xor(sum, 32);
        const float inv = 1.0f / sum;
#pragma unroll
        for (int mt = 0; mt < 4; ++mt)
#pragma unroll
            for (int i = 0; i < 4; ++i) {
                const int r = mt * 16 + 4 * g + i;
                *(u16*)(Qw + p * 128 + ((r * 2) ^ ((p & 7) << 4))) = f2bf(s[mt][nt][i] * inv);
            }
    }

    // ---- P3: ctx^T = V^T @ attn^T (verbatim) ----
    f32x4 c_[4][4];
#pragma unroll
    for (int mt = 0; mt < 4; ++mt)
#pragma unroll
        for (int nt = 0; nt < 4; ++nt)
            c_[mt][nt] = f32x4{0.f, 0.f, 0.f, 0.f};

#pragma unroll
    for (int ks2 = 0; ks2 < 2; ++ks2) {
        const int kcb = (ks2 * 32 + 8 * g) * 2;
        bf16x8 bs_[4];
#pragma unroll
        for (int nt = 0; nt < 4; ++nt)
            bs_[nt] = *(const bf16x8*)(Qw + (nt * 16 + lo16) * 128 + (kcb ^ xr));
#pragma unroll
        for (int mt = 0; mt < 4; ++mt)
#pragma unroll
            for (int nt = 0; nt < 4; ++nt)
                c_[mt][nt] = MFMA16(av[mt][ks2], bs_[nt], c_[mt][nt]);
    }

    // ---- NEW: wave-slice LDS transpose + coalesced 16B cb stores ----
    __syncthreads();   // all P-reads of Qw done (also orders cross-lane LDS)
    {
        u16* Cx = (u16*)Qw;   // reuse 8KB slice: Cx[p][d], chunk-swizzled
#pragma unroll
        for (int mt = 0; mt < 4; ++mt)
#pragma unroll
            for (int nt = 0; nt < 4; ++nt)
#pragma unroll
                for (int i = 0; i < 4; ++i) {
                    const int d = mt * 16 + 4 * g + i;   // ctx row = head-dim
                    const int p = nt * 16 + lo16;        // ctx col = token
                    Cx[p * 64 + (d ^ ((p & 7) << 3))] = f2bf(c_[mt][nt][i]);
                }
    }
    __syncthreads();   // Cx writes visible to all lanes of the wave
    {
        u16* Cx = (u16*)Qw;
        const size_t cbase = ((size_t)(b * 8 + w) * 4096 + P0) * 64;
#pragma unroll
        for (int it = 0; it < 8; ++it) {
            const int p = it * 8 + (lane >> 3);
            const int cc = lane & 7;
            uint4 v = *(uint4*)&Cx[p * 64 + ((cc ^ (p & 7)) * 8)];
            *(uint4*)(cb + cbase + (size_t)p * 64 + cc * 8) = v;
        }
    }
}

// ---------------------------------------------------------------------------
// Kernel B (R7): out-projection. Staging vectorized: uint4 loads from cb,
// uint4 LDS writes with the byte-identical R6-proven swizzle (XOR affects
// bits 4-6 only; each aligned 16B chunk maps intact). P4 + epilogue verbatim.
// ---------------------------------------------------------------------------
__global__ __launch_bounds__(512, 4) void frgca_oproj4(
    const u16* __restrict__ cb, const u16* __restrict__ wo,
    const float* __restrict__ out_b, const float* __restrict__ visual,
    float* __restrict__ out)
{
    __shared__ char regA[65536];

    const int tid = threadIdx.x;
    const int w = tid >> 6, lane = tid & 63;
    const int lo16 = lane & 15, g = lane >> 4;
    const int xr = (lo16 & 7) << 4;
    const int P0 = blockIdx.x * 64, b = blockIdx.y;
    const size_t vbase = ((size_t)(b * 4096 + P0)) * 512;

    // ---- vectorized cb -> LDS stage (exact vectorization of R6 scalar) ----
#pragma unroll
    for (int it = 0; it < 8; ++it) {
        const int flat = tid + it * 512;       // 16B-chunk id, 0..4095
        const int cc = flat & 7;               // chunk within row (d-chunk)
        const int p  = (flat >> 3) & 63;       // token
        const int h  = flat >> 9;              // head
        uint4 v = *(const uint4*)(cb + ((size_t)(b * 8 + h) * 4096 + P0 + p) * 64 + cc * 8);
        const int e2 = (h * 64 + cc * 8) * 2;  // byte offset of e-chunk
        *(uint4*)(regA + p * 1024 + (e2 ^ ((p & 7) << 4))) = v;
    }
    __syncthreads();

    const int e0 = w * 64;

    // ---- P4: out = ctx @ Wo^T + bo + visual (R6 verbatim) ----
    f32x4 o_[4][4];
#pragma unroll
    for (int mt = 0; mt < 4; ++mt)
#pragma unroll
        for (int nt = 0; nt < 4; ++nt)
            o_[mt][nt] = f32x4{0.f, 0.f, 0.f, 0.f};

    const u16* woR0 = wo + ((size_t)(e0 + 0 * 16 + lo16)) * 512;
    const u16* woR1 = wo + ((size_t)(e0 + 1 * 16 + lo16)) * 512;
    const u16* woR2 = wo + ((size_t)(e0 + 2 * 16 + lo16)) * 512;
    const u16* woR3 = wo + ((size_t)(e0 + 3 * 16 + lo16)) * 512;
    bf16x8 ob0 = *(const bf16x8*)&woR0[8 * g];
    bf16x8 ob1 = *(const bf16x8*)&woR1[8 * g];
    bf16x8 ob2 = *(const bf16x8*)&woR2[8 * g];
    bf16x8 ob3 = *(const bf16x8*)&woR3[8 * g];

#pragma unroll
    for (int ks = 0; ks < 16; ++ks) {
        const int kc = ks * 32 + 8 * g;
        bf16x8 cb0 = ob0, cb1 = ob1, cb2 = ob2, cb3 = ob3;
        if (ks < 15) {
            const int kn = kc + 32;
            ob0 = *(const bf16x8*)&woR0[kn];
            ob1 = *(const bf16x8*)&woR1[kn];
            ob2 = *(const bf16x8*)&woR2[kn];
            ob3 = *(const bf16x8*)&woR3[kn];
        }
        bf16x8 a[4];
#pragma unroll
        for (int mt = 0; mt < 4; ++mt)
            a[mt] = *(const bf16x8*)(regA + (mt * 16 + lo16) * 1024 + ((kc * 2) ^ xr));
#pragma unroll
        for (int mt = 0; mt < 4; ++mt) {
            o_[mt][0] = MFMA16(a[mt], cb0, o_[mt][0]);
            o_[mt][1] = MFMA16(a[mt], cb1, o_[mt][1]);
            o_[mt][2] = MFMA16(a[mt], cb2, o_[mt][2]);
            o_[mt][3] = MFMA16(a[mt], cb3, o_[mt][3]);
        }
    }

#pragma unroll
    for (int nt = 0; nt < 4; ++nt) {
        const int e = e0 + nt * 16 + lo16;
        const float bo = out_b[e];
#pragma unroll
        for (int mt = 0; mt < 4; ++mt)
#pragma unroll
            for (int i = 0; i < 4; ++i) {
                const int p = mt * 16 + 4 * g + i;
                const size_t gid = vbase + (size_t)p * 512 + e;
                out[gid] = o_[mt][nt][i] + bo + visual[gid];
            }
    }
}

// ---------------------------------------------------------------------------
// Fallback fused kernel (R2, proven) — used only if ws too small.
// ---------------------------------------------------------------------------
__global__ __launch_bounds__(512, 4) void frgca_main(
    const float* __restrict__ visual,
    const float* __restrict__ mask,
    const float* __restrict__ in_b,
    const float* __restrict__ out_b,
    const u16* __restrict__ wq, const u16* __restrict__ wo,
    const u16* __restrict__ kt, const u16* __restrict__ vt,
    float* __restrict__ out)
{
    __shared__ char regA[65536];
    __shared__ float Ms[4096];

    const int tid = threadIdx.x;
    const int w = tid >> 6, lane = tid & 63;
    const int lo16 = lane & 15, g = lane >> 4;
    const int xr = (lo16 & 7) << 4;
    const int pt = blockIdx.x, b = blockIdx.y;
    const int P0 = pt * 64;
    const size_t vbase = ((size_t)(b * 4096 + P0)) * 512;

    {
        const float4* v4 = (const float4*)(visual + vbase);
#pragma unroll
        for (int i = 0; i < 16; ++i) {
            int f4  = tid + i * 512;
            int row = f4 >> 7, c4 = f4 & 127;
            float4 v = v4[f4];
            ushort4 o;
            o.x = f2bf(v.x); o.y = f2bf(v.y); o.z = f2bf(v.z); o.w = f2bf(v.w);
            *(ushort4*)(regA + row * 1024 + ((c4 * 8) ^ ((row & 7) << 4))) = o;
        }
        const float4* m4 = (const float4*)(mask + ((size_t)(b * 4096 + P0)) * 64);
#pragma unroll
        for (int i = 0; i < 2; ++i) {
            int f4 = tid + i * 512;
            int p = f4 >> 4, r0 = (f4 & 15) * 4;
            float4 v = m4[f4];
            int pb = p * 64, px = p & 31;
            Ms[pb + ((r0 + 0) ^ px)] = (1.0f - v.x) * -1e9f;
            Ms[pb + ((r0 + 1) ^ px)] = (1.0f - v.y) * -1e9f;
            Ms[pb + ((r0 + 2) ^ px)] = (1.0f - v.z) * -1e9f;
            Ms[pb + ((r0 + 3) ^ px)] = (1.0f - v.w) * -1e9f;
        }
    }
    __syncthreads();

    const int e0 = w * 64;

    f32x4 acc[4][4];
#pragma unroll
    for (int mt = 0; mt < 4; ++mt)
#pragma unroll
        for (int nt = 0; nt < 4; ++nt)
            acc[mt][nt] = f32x4{0.f, 0.f, 0.f, 0.f};

    const u16* wqR0 = wq + ((size_t)(e0 + 0 * 16 + lo16)) * 512;
    const u16* wqR1 = wq + ((size_t)(e0 + 1 * 16 + lo16)) * 512;
    const u16* wqR2 = wq + ((size_t)(e0 + 2 * 16 + lo16)) * 512;
    const u16* wqR3 = wq + ((size_t)(e0 + 3 * 16 + lo16)) * 512;
    bf16x8 nb0 = *(const bf16x8*)&wqR0[8 * g];
    bf16x8 nb1 = *(const bf16x8*)&wqR1[8 * g];
    bf16x8 nb2 = *(const bf16x8*)&wqR2[8 * g];
    bf16x8 nb3 = *(const bf16x8*)&wqR3[8 * g];

#pragma unroll
    for (int ks = 0; ks < 16; ++ks) {
        const int kc = ks * 32 + 8 * g;
        bf16x8 cb0 = nb0, cb1 = nb1, cb2 = nb2, cb3 = nb3;
        if (ks < 15) {
            const int kn = kc + 32;
            nb0 = *(const bf16x8*)&wqR0[kn];
            nb1 = *(const bf16x8*)&wqR1[kn];
            nb2 = *(const bf16x8*)&wqR2[kn];
            nb3 = *(const bf16x8*)&wqR3[kn];
        }
        bf16x8 a[4];
#pragma unroll
        for (int mt = 0; mt < 4; ++mt)
            a[mt] = *(const bf16x8*)(regA + (mt * 16 + lo16) * 1024 + ((kc * 2) ^ xr));
#pragma unroll
        for (int mt = 0; mt < 4; ++mt) {
            acc[mt][0] = MFMA16(a[mt], cb0, acc[mt][0]);
            acc[mt][1] = MFMA16(a[mt], cb1, acc[mt][1]);
            acc[mt][2] = MFMA16(a[mt], cb2, acc[mt][2]);
            acc[mt][3] = MFMA16(a[mt], cb3, acc[mt][3]);
        }
    }

    const u16* KtH = kt + ((size_t)(b * 8 + w)) * 4096;
    bf16x8 ak[4][2];
#pragma unroll
    for (int ks2 = 0; ks2 < 2; ++ks2)
#pragma unroll
        for (int mt = 0; mt < 4; ++mt)
            ak[mt][ks2] = *(const bf16x8*)&KtH[(mt * 16 + lo16) * 64 + ks2 * 32 + 8 * g];

#pragma unroll
    for (int nt = 0; nt < 4; ++nt) {
        const float bq = in_b[e0 + nt * 16 + lo16];
#pragma unroll
        for (int mt = 0; mt < 4; ++mt)
#pragma unroll
            for (int i = 0; i < 4; ++i)
                acc[mt][nt][i] += bq;
    }
    __syncthreads();

    char* Qw = regA + w * 8192;
#pragma unroll
    for (int mt = 0; mt < 4; ++mt)
#pragma unroll
        for (int nt = 0; nt < 4; ++nt)
#pragma unroll
            for (int i = 0; i < 4; ++i) {
                const int p = mt * 16 + 4 * g + i;
                const int d = nt * 16 + lo16;
                *(u16*)(Qw + p * 128 + ((d * 2) ^ ((p & 7) << 4))) = f2bf(acc[mt][nt][i]);
            }

    f32x4 s[4][4];
#pragma unroll
    for (int mt = 0; mt < 4; ++mt)
#pragma unroll
        for (int nt = 0; nt < 4; ++nt)
            s[mt][nt] = f32x4{0.f, 0.f, 0.f, 0.f};

#pragma unroll
    for (int ks2 = 0; ks2 < 2; ++ks2) {
        const int kcb = (ks2 * 32 + 8 * g) * 2;
        bf16x8 bq_[4];
#pragma unroll
        for (int nt = 0; nt < 4; ++nt)
            bq_[nt] = *(const bf16x8*)(Qw + (nt * 16 + lo16) * 128 + (kcb ^ xr));
#pragma unroll
        for (int mt = 0; mt < 4; ++mt)
#pragma unroll
            for (int nt = 0; nt < 4; ++nt)
                s[mt][nt] = MFMA16(ak[mt][ks2], bq_[nt], s[mt][nt]);
    }

    const u16* VtH = vt + ((size_t)(b * 8 + w)) * 4096;
    bf16x8 av[4][2];
#pragma unroll
    for (int ks2 = 0; ks2 < 2; ++ks2)
#pragma unroll
        for (int mt = 0; mt < 4; ++mt)
            av[mt][ks2] = *(const bf16x8*)&VtH[(mt * 16 + lo16) * 64 + ks2 * 32 + 8 * g];

#pragma unroll
    for (int nt = 0; nt < 4; ++nt) {
        const int p = nt * 16 + lo16;
        const int pb = p * 64, px = p & 31;
        float mx = -3.4e38f;
#pragma unroll
        for (int mt = 0; mt < 4; ++mt)
#pragma unroll
            for (int i = 0; i < 4; ++i) {
                float v = s[mt][nt][i] * 0.125f + Ms[pb + ((mt * 16 + 4 * g + i) ^ px)];
                s[mt][nt][i] = v;
                mx = fmaxf(mx, v);
            }
        mx = fmaxf(mx, __shfl_xor(mx, 16));
        mx = fmaxf(mx, __shfl_xor(mx, 32));
        float sum = 0.f;
#pragma unroll
        for (int mt = 0; mt < 4; ++mt)
#pragma unroll
            for (int i = 0; i < 4; ++i) {
                float ev = __expf(s[mt][nt][i] - mx);
                s[mt][nt][i] = ev;
                sum += ev;
            }
        sum += __shfl_xor(sum, 16);
        sum += __shfl_xor(sum, 32);
        const float inv = 1.0f / sum;
#pragma unroll
        for (int mt = 0; mt < 4; ++mt)
#pragma unroll
            for (int i = 0; i < 4; ++i) {
                const int r = mt * 16 + 4 * g + i;
                *(u16*)(Qw + p * 128 + ((r * 2) ^ ((p & 7) << 4))) = f2bf(s[mt][nt][i] * inv);
            }
    }

    f32x4 c_[4][4];
#pragma unroll
    for (int mt = 0; mt < 4; ++mt)
#pragma unroll
        for (int nt = 0; nt < 4; ++nt)
            c_[mt][nt] = f32x4{0.f, 0.f, 0.f, 0.f};

#pragma unroll
    for (int ks2 = 0; ks2 < 2; ++ks2) {
        const int kcb = (ks2 * 32 + 8 * g) * 2;
        bf16x8 bs_[4];
#pragma unroll
        for (int nt = 0; nt < 4; ++nt)
            bs_[nt] = *(const bf16x8*)(Qw + (nt * 16 + lo16) * 128 + (kcb ^ xr));
#pragma unroll
        for (int mt = 0; mt < 4; ++mt)
#pragma unroll
            for (int nt = 0; nt < 4; ++nt)
                c_[mt][nt] = MFMA16(av[mt][ks2], bs_[nt], c_[mt][nt]);
    }
    __syncthreads();

#pragma unroll
    for (int mt = 0; mt < 4; ++mt)
#pragma unroll
        for (int nt = 0; nt < 4; ++nt)
#pragma unroll
            for (int i = 0; i < 4; ++i) {
                const int p = nt * 16 + lo16;
                const int c = e0 + mt * 16 + 4 * g + i;
                *(u16*)(regA + p * 1024 + ((c * 2) ^ ((p & 7) << 4))) = f2bf(c_[mt][nt][i]);
            }
    __syncthreads();

    f32x4 o_[4][4];
#pragma unroll
    for (int mt = 0; mt < 4; ++mt)
#pragma unroll
        for (int nt = 0; nt < 4; ++nt)
            o_[mt][nt] = f32x4{0.f, 0.f, 0.f, 0.f};

    const u16* woR0 = wo + ((size_t)(e0 + 0 * 16 + lo16)) * 512;
    const u16* woR1 = wo + ((size_t)(e0 + 1 * 16 + lo16)) * 512;
    const u16* woR2 = wo + ((size_t)(e0 + 2 * 16 + lo16)) * 512;
    const u16* woR3 = wo + ((size_t)(e0 + 3 * 16 + lo16)) * 512;
    bf16x8 ob0 = *(const bf16x8*)&woR0[8 * g];
    bf16x8 ob1 = *(const bf16x8*)&woR1[8 * g];
    bf16x8 ob2 = *(const bf16x8*)&woR2[8 * g];
    bf16x8 ob3 = *(const bf16x8*)&woR3[8 * g];

#pragma unroll
    for (int ks = 0; ks < 16; ++ks) {
        const int kc = ks * 32 + 8 * g;
        bf16x8 cb0 = ob0, cb1 = ob1, cb2 = ob2, cb3 = ob3;
        if (ks < 15) {
            const int kn = kc + 32;
            ob0 = *(const bf16x8*)&woR0[kn];
            ob1 = *(const bf16x8*)&woR1[kn];
            ob2 = *(const bf16x8*)&woR2[kn];
            ob3 = *(const bf16x8*)&woR3[kn];
        }
        bf16x8 a[4];
#pragma unroll
        for (int mt = 0; mt < 4; ++mt)
            a[mt] = *(const bf16x8*)(regA + (mt * 16 + lo16) * 1024 + ((kc * 2) ^ xr));
#pragma unroll
        for (int mt = 0; mt < 4; ++mt) {
            o_[mt][0] = MFMA16(a[mt], cb0, o_[mt][0]);
            o_[mt][1] = MFMA16(a[mt], cb1, o_[mt][1]);
            o_[mt][2] = MFMA16(a[mt], cb2, o_[mt][2]);
            o_[mt][3] = MFMA16(a[mt], cb3, o_[mt][3]);
        }
    }

#pragma unroll
    for (int nt = 0; nt < 4; ++nt) {
        const int e = e0 + nt * 16 + lo16;
        const float bo = out_b[e];
#pragma unroll
        for (int mt = 0; mt < 4; ++mt)
#pragma unroll
            for (int i = 0; i < 4; ++i) {
                const int p = mt * 16 + 4 * g + i;
                const size_t gid = vbase + (size_t)p * 512 + e;
                out[gid] = o_[mt][nt][i] + bo + visual[gid];
            }
    }
}

extern "C" void kernel_launch(void* const* d_in, const int* in_sizes, int n_in,
                              void* d_out, int out_size, void* d_ws, size_t ws_size,
                              hipStream_t stream) {
    const float* visual = (const float*)d_in[0];
    const float* region = (const float*)d_in[1];
    const float* mask   = (const float*)d_in[2];
    const float* in_w   = (const float*)d_in[3];
    const float* in_b   = (const float*)d_in[4];
    const float* out_w  = (const float*)d_in[5];
    const float* out_b  = (const float*)d_in[6];
    float* out = (float*)d_out;

    char* ws = (char*)d_ws;
    u16* wq = (u16*)(ws + 0);          // 512 KB
    u16* wo = (u16*)(ws + 524288);     // 512 KB
    u16* kt = (u16*)(ws + 1048576);    // 2 MB  [b][h][r][d]
    u16* vt = (u16*)(ws + 3145728);    // 2 MB  [b][h][d][r]
    u16* cbp = (u16*)(ws + 5242880);   // 128 MiB [b][h][p][d]
    const size_t REQ = 5242880ull + 134217728ull;

    frgca_prep<<<dim3(160), dim3(256), 0, stream>>>(region, in_w, in_b, out_w, wq, wo, kt, vt);

    if (ws_size >= REQ) {
        frgca_qattn<<<dim3(64, 32), dim3(512), 0, stream>>>(visual, mask, in_b, wq, kt, vt, cbp);
        frgca_oproj4<<<dim3(64, 32), dim3(512), 0, stream>>>(cbp, wo, out_b, visual, out);
    } else {
        frgca_main<<<dim3(64, 32), dim3(512), 0, stream>>>(visual, mask, in_b, out_b, wq, wo, kt, vt, out);
    }
}

// Round 8
// 492.397 us; speedup vs baseline: 1.3106x; 1.3106x over previous
//
#include <hip/hip_runtime.h>
#include <hip/hip_bf16.h>

typedef unsigned short u16;
typedef unsigned int u32;

using bf16x8 = __attribute__((ext_vector_type(8))) short;
using f32x4  = __attribute__((ext_vector_type(4))) float;

#define MFMA16(a, b, c) __builtin_amdgcn_mfma_f32_16x16x32_bf16((a), (b), (c), 0, 0, 0)

__device__ __forceinline__ u16 f2bf(float f) {
    u32 u = __builtin_bit_cast(u32, f);
    u = (u + 0x7fffu + ((u >> 16) & 1u)) >> 16;
    return (u16)u;
}

// global -> LDS direct copy, 16B per lane. LDS dest wave-uniform; HW adds lane*16.
__device__ __forceinline__ void gload16(const void* g, void* l) {
    __builtin_amdgcn_global_load_lds(
        (const __attribute__((address_space(1))) u32*)g,
        (__attribute__((address_space(3))) u32*)l, 16, 0, 0);
}

// ---------------------------------------------------------------------------
// Prep kernel (unchanged, proven): weight cvt + K/V projection.
// ---------------------------------------------------------------------------
__global__ __launch_bounds__(256, 2) void frgca_prep(
    const float* __restrict__ region,
    const float* __restrict__ in_w,
    const float* __restrict__ in_b,
    const float* __restrict__ out_w,
    u16* __restrict__ wq, u16* __restrict__ wo,
    u16* __restrict__ kt, u16* __restrict__ vt)
{
    __shared__ u16 As2[64 * 520];
    const int tid = threadIdx.x;
    const int bid = blockIdx.x;

    if (bid < 32) {
        const float4* w4q = (const float4*)in_w;
        const float4* w4o = (const float4*)out_w;
        int t = bid * 256 + tid;
#pragma unroll
        for (int i = 0; i < 16; ++i) {
            int idx = t + i * 8192;
            float4 v;
            u16* dst;
            if (idx < 65536) { v = w4q[idx]; dst = wq + idx * 4; }
            else             { v = w4o[idx - 65536]; dst = wo + (idx - 65536) * 4; }
            ushort4 o;
            o.x = f2bf(v.x); o.y = f2bf(v.y); o.z = f2bf(v.z); o.w = f2bf(v.w);
            *(ushort4*)dst = o;
        }
        return;
    }

    const int t2 = bid - 32;
    const int b  = t2 >> 2;
    const int nc = t2 & 3;

    {
        const float4* r4 = (const float4*)(region + (size_t)b * 64 * 512);
#pragma unroll
        for (int i = 0; i < 32; ++i) {
            int f4  = tid + i * 256;
            int row = f4 >> 7;
            int c4  = f4 & 127;
            float4 v = r4[f4];
            ushort4 o;
            o.x = f2bf(v.x); o.y = f2bf(v.y); o.z = f2bf(v.z); o.w = f2bf(v.w);
            *(ushort4*)&As2[row * 520 + c4 * 4] = o;
        }
    }
    __syncthreads();

    const int lane = tid & 63, w = tid >> 6;
    const int lo16 = lane & 15, g = lane >> 4;
    const int e0 = nc * 256 + w * 64;

    f32x4 acc[4][4];
#pragma unroll
    for (int mt = 0; mt < 4; ++mt)
#pragma unroll
        for (int nt = 0; nt < 4; ++nt)
            acc[mt][nt] = f32x4{0.f, 0.f, 0.f, 0.f};

    const float* w2 = in_w + 512 * 512;

#pragma unroll 2
    for (int ks = 0; ks < 16; ++ks) {
        const int kc = ks * 32 + 8 * g;
        bf16x8 a[4], bb[4];
#pragma unroll
        for (int mt = 0; mt < 4; ++mt)
            a[mt] = *(const bf16x8*)&As2[(mt * 16 + lo16) * 520 + kc];
#pragma unroll
        for (int nt = 0; nt < 4; ++nt) {
            const int e = e0 + nt * 16 + lo16;
            const float* src = w2 + (size_t)e * 512 + kc;
            float4 v0 = *(const float4*)src;
            float4 v1 = *(const float4*)(src + 4);
            bf16x8 bv;
            bv[0] = (short)f2bf(v0.x); bv[1] = (short)f2bf(v0.y);
            bv[2] = (short)f2bf(v0.z); bv[3] = (short)f2bf(v0.w);
            bv[4] = (short)f2bf(v1.x); bv[5] = (short)f2bf(v1.y);
            bv[6] = (short)f2bf(v1.z); bv[7] = (short)f2bf(v1.w);
            bb[nt] = bv;
        }
#pragma unroll
        for (int mt = 0; mt < 4; ++mt)
#pragma unroll
            for (int nt = 0; nt < 4; ++nt)
                acc[mt][nt] = MFMA16(a[mt], bb[nt], acc[mt][nt]);
    }

#pragma unroll
    for (int nt = 0; nt < 4; ++nt) {
        const int e = e0 + nt * 16 + lo16;
        const float bias = in_b[512 + e];
#pragma unroll
        for (int mt = 0; mt < 4; ++mt)
#pragma unroll
            for (int i = 0; i < 4; ++i) {
                const int r = mt * 16 + 4 * g + i;
                const u16 o = f2bf(acc[mt][nt][i] + bias);
                if (e < 512) {
                    const int h = e >> 6, d = e & 63;
                    kt[(((size_t)(b * 8 + h)) * 64 + r) * 64 + d] = o;
                } else {
                    const int e2 = e - 512;
                    const int h = e2 >> 6, d = e2 & 63;
                    vt[(((size_t)(b * 8 + h)) * 64 + d) * 64 + r] = o;
                }
            }
    }
}

// ---------------------------------------------------------------------------
// Kernel A (R7-proven, unchanged): fused Q-proj + attention, coalesced cb out.
// ---------------------------------------------------------------------------
__global__ __launch_bounds__(512, 4) void frgca_qattn(
    const float* __restrict__ visual,
    const float* __restrict__ mask,
    const float* __restrict__ in_b,
    const u16* __restrict__ wq,
    const u16* __restrict__ kt, const u16* __restrict__ vt,
    u16* __restrict__ cb)
{
    __shared__ char regA[65536];
    __shared__ float Ms[4096];

    const int tid = threadIdx.x;
    const int w = tid >> 6, lane = tid & 63;
    const int lo16 = lane & 15, g = lane >> 4;
    const int xr = (lo16 & 7) << 4;
    const int pt = blockIdx.x, b = blockIdx.y;
    const int P0 = pt * 64;
    const size_t vbase = ((size_t)(b * 4096 + P0)) * 512;

    {
        const float4* v4 = (const float4*)(visual + vbase);
#pragma unroll
        for (int i = 0; i < 16; ++i) {
            int f4  = tid + i * 512;
            int row = f4 >> 7, c4 = f4 & 127;
            float4 v = v4[f4];
            ushort4 o;
            o.x = f2bf(v.x); o.y = f2bf(v.y); o.z = f2bf(v.z); o.w = f2bf(v.w);
            *(ushort4*)(regA + row * 1024 + ((c4 * 8) ^ ((row & 7) << 4))) = o;
        }
        const float4* m4 = (const float4*)(mask + ((size_t)(b * 4096 + P0)) * 64);
#pragma unroll
        for (int i = 0; i < 2; ++i) {
            int f4 = tid + i * 512;
            int p = f4 >> 4, r0 = (f4 & 15) * 4;
            float4 v = m4[f4];
            int pb = p * 64, px = p & 31;
            Ms[pb + ((r0 + 0) ^ px)] = (1.0f - v.x) * -1e9f;
            Ms[pb + ((r0 + 1) ^ px)] = (1.0f - v.y) * -1e9f;
            Ms[pb + ((r0 + 2) ^ px)] = (1.0f - v.z) * -1e9f;
            Ms[pb + ((r0 + 3) ^ px)] = (1.0f - v.w) * -1e9f;
        }
    }
    __syncthreads();

    const int e0 = w * 64;

    f32x4 acc[4][4];
#pragma unroll
    for (int mt = 0; mt < 4; ++mt)
#pragma unroll
        for (int nt = 0; nt < 4; ++nt)
            acc[mt][nt] = f32x4{0.f, 0.f, 0.f, 0.f};

    const u16* wqR0 = wq + ((size_t)(e0 + 0 * 16 + lo16)) * 512;
    const u16* wqR1 = wq + ((size_t)(e0 + 1 * 16 + lo16)) * 512;
    const u16* wqR2 = wq + ((size_t)(e0 + 2 * 16 + lo16)) * 512;
    const u16* wqR3 = wq + ((size_t)(e0 + 3 * 16 + lo16)) * 512;
    bf16x8 nb0 = *(const bf16x8*)&wqR0[8 * g];
    bf16x8 nb1 = *(const bf16x8*)&wqR1[8 * g];
    bf16x8 nb2 = *(const bf16x8*)&wqR2[8 * g];
    bf16x8 nb3 = *(const bf16x8*)&wqR3[8 * g];

#pragma unroll
    for (int ks = 0; ks < 16; ++ks) {
        const int kc = ks * 32 + 8 * g;
        bf16x8 cb0 = nb0, cb1 = nb1, cb2 = nb2, cb3 = nb3;
        if (ks < 15) {
            const int kn = kc + 32;
            nb0 = *(const bf16x8*)&wqR0[kn];
            nb1 = *(const bf16x8*)&wqR1[kn];
            nb2 = *(const bf16x8*)&wqR2[kn];
            nb3 = *(const bf16x8*)&wqR3[kn];
        }
        bf16x8 a[4];
#pragma unroll
        for (int mt = 0; mt < 4; ++mt)
            a[mt] = *(const bf16x8*)(regA + (mt * 16 + lo16) * 1024 + ((kc * 2) ^ xr));
#pragma unroll
        for (int mt = 0; mt < 4; ++mt) {
            acc[mt][0] = MFMA16(a[mt], cb0, acc[mt][0]);
            acc[mt][1] = MFMA16(a[mt], cb1, acc[mt][1]);
            acc[mt][2] = MFMA16(a[mt], cb2, acc[mt][2]);
            acc[mt][3] = MFMA16(a[mt], cb3, acc[mt][3]);
        }
    }

    const u16* KtH = kt + ((size_t)(b * 8 + w)) * 4096;
    bf16x8 ak[4][2];
#pragma unroll
    for (int ks2 = 0; ks2 < 2; ++ks2)
#pragma unroll
        for (int mt = 0; mt < 4; ++mt)
            ak[mt][ks2] = *(const bf16x8*)&KtH[(mt * 16 + lo16) * 64 + ks2 * 32 + 8 * g];

#pragma unroll
    for (int nt = 0; nt < 4; ++nt) {
        const float bq = in_b[e0 + nt * 16 + lo16];
#pragma unroll
        for (int mt = 0; mt < 4; ++mt)
#pragma unroll
            for (int i = 0; i < 4; ++i)
                acc[mt][nt][i] += bq;
    }
    __syncthreads();

    char* Qw = regA + w * 8192;
#pragma unroll
    for (int mt = 0; mt < 4; ++mt)
#pragma unroll
        for (int nt = 0; nt < 4; ++nt)
#pragma unroll
            for (int i = 0; i < 4; ++i) {
                const int p = mt * 16 + 4 * g + i;
                const int d = nt * 16 + lo16;
                *(u16*)(Qw + p * 128 + ((d * 2) ^ ((p & 7) << 4))) = f2bf(acc[mt][nt][i]);
            }

    f32x4 s[4][4];
#pragma unroll
    for (int mt = 0; mt < 4; ++mt)
#pragma unroll
        for (int nt = 0; nt < 4; ++nt)
            s[mt][nt] = f32x4{0.f, 0.f, 0.f, 0.f};

#pragma unroll
    for (int ks2 = 0; ks2 < 2; ++ks2) {
        const int kcb = (ks2 * 32 + 8 * g) * 2;
        bf16x8 bq_[4];
#pragma unroll
        for (int nt = 0; nt < 4; ++nt)
            bq_[nt] = *(const bf16x8*)(Qw + (nt * 16 + lo16) * 128 + (kcb ^ xr));
#pragma unroll
        for (int mt = 0; mt < 4; ++mt)
#pragma unroll
            for (int nt = 0; nt < 4; ++nt)
                s[mt][nt] = MFMA16(ak[mt][ks2], bq_[nt], s[mt][nt]);
    }

    const u16* VtH = vt + ((size_t)(b * 8 + w)) * 4096;
    bf16x8 av[4][2];
#pragma unroll
    for (int ks2 = 0; ks2 < 2; ++ks2)
#pragma unroll
        for (int mt = 0; mt < 4; ++mt)
            av[mt][ks2] = *(const bf16x8*)&VtH[(mt * 16 + lo16) * 64 + ks2 * 32 + 8 * g];

#pragma unroll
    for (int nt = 0; nt < 4; ++nt) {
        const int p = nt * 16 + lo16;
        const int pb = p * 64, px = p & 31;
        float mx = -3.4e38f;
#pragma unroll
        for (int mt = 0; mt < 4; ++mt)
#pragma unroll
            for (int i = 0; i < 4; ++i) {
                float v = s[mt][nt][i] * 0.125f + Ms[pb + ((mt * 16 + 4 * g + i) ^ px)];
                s[mt][nt][i] = v;
                mx = fmaxf(mx, v);
            }
        mx = fmaxf(mx, __shfl_xor(mx, 16));
        mx = fmaxf(mx, __shfl_xor(mx, 32));
        float sum = 0.f;
#pragma unroll
        for (int mt = 0; mt < 4; ++mt)
#pragma unroll
            for (int i = 0; i < 4; ++i) {
                float ev = __expf(s[mt][nt][i] - mx);
                s[mt][nt][i] = ev;
                sum += ev;
            }
        sum += __shfl_xor(sum, 16);
        sum += __shfl_xor(sum, 32);
        const float inv = 1.0f / sum;
#pragma unroll
        for (int mt = 0; mt < 4; ++mt)
#pragma unroll
            for (int i = 0; i < 4; ++i) {
                const int r = mt * 16 + 4 * g + i;
                *(u16*)(Qw + p * 128 + ((r * 2) ^ ((p & 7) << 4))) = f2bf(s[mt][nt][i] * inv);
            }
    }

    f32x4 c_[4][4];
#pragma unroll
    for (int mt = 0; mt < 4; ++mt)
#pragma unroll
        for (int nt = 0; nt < 4; ++nt)
            c_[mt][nt] = f32x4{0.f, 0.f, 0.f, 0.f};

#pragma unroll
    for (int ks2 = 0; ks2 < 2; ++ks2) {
        const int kcb = (ks2 * 32 + 8 * g) * 2;
        bf16x8 bs_[4];
#pragma unroll
        for (int nt = 0; nt < 4; ++nt)
            bs_[nt] = *(const bf16x8*)(Qw + (nt * 16 + lo16) * 128 + (kcb ^ xr));
#pragma unroll
        for (int mt = 0; mt < 4; ++mt)
#pragma unroll
            for (int nt = 0; nt < 4; ++nt)
                c_[mt][nt] = MFMA16(av[mt][ks2], bs_[nt], c_[mt][nt]);
    }

    __syncthreads();
    {
        u16* Cx = (u16*)Qw;
#pragma unroll
        for (int mt = 0; mt < 4; ++mt)
#pragma unroll
            for (int nt = 0; nt < 4; ++nt)
#pragma unroll
                for (int i = 0; i < 4; ++i) {
                    const int d = mt * 16 + 4 * g + i;
                    const int p = nt * 16 + lo16;
                    Cx[p * 64 + (d ^ ((p & 7) << 3))] = f2bf(c_[mt][nt][i]);
                }
    }
    __syncthreads();
    {
        u16* Cx = (u16*)Qw;
        const size_t cbase = ((size_t)(b * 8 + w) * 4096 + P0) * 64;
#pragma unroll
        for (int it = 0; it < 8; ++it) {
            const int p = it * 8 + (lane >> 3);
            const int cc = lane & 7;
            uint4 v = *(uint4*)&Cx[p * 64 + ((cc ^ (p & 7)) * 8)];
            *(uint4*)(cb + cbase + (size_t)p * 64 + cc * 8) = v;
        }
    }
}

// ---------------------------------------------------------------------------
// Kernel B (R8): out-projection GEMM, m97-pattern.
// M=131072, N=512, K=512(e). Tile 128x256, BK=32, 8 waves (2x4 of 64x64).
// Both operands via LINEAR global_load_lds, double-buffered (48KB LDS).
// A = cb[b][h][p][d] (K-slice ks -> h=ks>>1, d-half=ks&1); B = wo row-major.
// Epilogue: out = acc + bo + visual (proven pattern).
// ---------------------------------------------------------------------------
__global__ __launch_bounds__(512) void frgca_oproj5(
    const u16* __restrict__ cb, const u16* __restrict__ wo,
    const float* __restrict__ out_b, const float* __restrict__ visual,
    float* __restrict__ out)
{
    __shared__ char Lds[49152];   // A: buf*8192 (2x8KB); B: 16384 + buf*16384 (2x16KB)

    const int tid = threadIdx.x;
    const int w = tid >> 6, lane = tid & 63;
    const int lo16 = lane & 15, g = lane >> 4;
    const int wr = w >> 2;        // 0..1  (M half)
    const int wc = w & 3;         // 0..3  (N quarter)
    const int M0 = blockIdx.x * 128;
    const int N0 = blockIdx.y * 256;
    const int b = M0 >> 12, p0 = M0 & 4095;

    // staging: 24 x 1KB chunks per K-step (A:8, B:16); wave w does chunks 3w..3w+2
    // chunk-local: lane l covers row 16*chunk + (l>>2), colbyte (l&3)*16
    const int srow = lane >> 2;            // 0..15
    const int scol = (lane & 3) * 16;      // 0,16,32,48
    const char* cbb = (const char*)cb;
    const char* wob = (const char*)wo;

    // issue the 3 staging calls of this wave for K-step ks into buffer buf
#define STAGE(ks, buf)                                                          \
    {                                                                           \
        _Pragma("unroll")                                                       \
        for (int k3 = 0; k3 < 3; ++k3) {                                        \
            const int c = w * 3 + k3;                                           \
            if (c < 8) {                                                        \
                const int row = c * 16 + srow;                                  \
                const char* src = cbb +                                         \
                    ((size_t)(b * 8 + ((ks) >> 1)) * 4096 + p0 + row) * 128 +   \
                    ((ks) & 1) * 64 + scol;                                     \
                gload16(src, Lds + (buf) * 8192 + c * 1024);                    \
            } else {                                                            \
                const int cbk = c - 8;                                          \
                const int row = cbk * 16 + srow;                                \
                const char* src = wob + (size_t)(N0 + row) * 1024 +             \
                    (size_t)(ks) * 64 + scol;                                   \
                gload16(src, Lds + 16384 + (buf) * 16384 + cbk * 1024);         \
            }                                                                   \
        }                                                                       \
    }

    f32x4 acc[4][4];
#pragma unroll
    for (int mt = 0; mt < 4; ++mt)
#pragma unroll
        for (int nt = 0; nt < 4; ++nt)
            acc[mt][nt] = f32x4{0.f, 0.f, 0.f, 0.f};

    STAGE(0, 0);
    __syncthreads();

    int cur = 0;
#pragma unroll
    for (int ks = 0; ks < 16; ++ks) {
        if (ks < 15) STAGE(ks + 1, cur ^ 1);
        const char* At = Lds + cur * 8192;
        const char* Bt = Lds + 16384 + cur * 16384;
        bf16x8 a[4], bb[4];
#pragma unroll
        for (int mt = 0; mt < 4; ++mt) {
            const int row = wr * 64 + mt * 16 + lo16;
            a[mt] = *(const bf16x8*)(At + row * 64 + 16 * g);
        }
#pragma unroll
        for (int nt = 0; nt < 4; ++nt) {
            const int row = wc * 64 + nt * 16 + lo16;
            bb[nt] = *(const bf16x8*)(Bt + row * 64 + 16 * g);
        }
#pragma unroll
        for (int nt = 0; nt < 4; ++nt)
#pragma unroll
            for (int mt = 0; mt < 4; ++mt)
                acc[mt][nt] = MFMA16(a[mt], bb[nt], acc[mt][nt]);
        __syncthreads();
        cur ^= 1;
    }
#undef STAGE

    // epilogue: bias + residual (proven pattern)
#pragma unroll
    for (int nt = 0; nt < 4; ++nt) {
        const int e = N0 + wc * 64 + nt * 16 + lo16;
        const float bo = out_b[e];
#pragma unroll
        for (int mt = 0; mt < 4; ++mt)
#pragma unroll
            for (int i = 0; i < 4; ++i) {
                const size_t m = (size_t)M0 + wr * 64 + mt * 16 + 4 * g + i;
                const size_t gid = m * 512 + e;
                out[gid] = acc[mt][nt][i] + bo + visual[gid];
            }
    }
}

// ---------------------------------------------------------------------------
// Fallback fused kernel (R2, proven) — used only if ws too small.
// ---------------------------------------------------------------------------
__global__ __launch_bounds__(512, 4) void frgca_main(
    const float* __restrict__ visual,
    const float* __restrict__ mask,
    const float* __restrict__ in_b,
    const float* __restrict__ out_b,
    const u16* __restrict__ wq, const u16* __restrict__ wo,
    const u16* __restrict__ kt, const u16* __restrict__ vt,
    float* __restrict__ out)
{
    __shared__ char regA[65536];
    __shared__ float Ms[4096];

    const int tid = threadIdx.x;
    const int w = tid >> 6, lane = tid & 63;
    const int lo16 = lane & 15, g = lane >> 4;
    const int xr = (lo16 & 7) << 4;
    const int pt = blockIdx.x, b = blockIdx.y;
    const int P0 = pt * 64;
    const size_t vbase = ((size_t)(b * 4096 + P0)) * 512;

    {
        const float4* v4 = (const float4*)(visual + vbase);
#pragma unroll
        for (int i = 0; i < 16; ++i) {
            int f4  = tid + i * 512;
            int row = f4 >> 7, c4 = f4 & 127;
            float4 v = v4[f4];
            ushort4 o;
            o.x = f2bf(v.x); o.y = f2bf(v.y); o.z = f2bf(v.z); o.w = f2bf(v.w);
            *(ushort4*)(regA + row * 1024 + ((c4 * 8) ^ ((row & 7) << 4))) = o;
        }
        const float4* m4 = (const float4*)(mask + ((size_t)(b * 4096 + P0)) * 64);
#pragma unroll
        for (int i = 0; i < 2; ++i) {
            int f4 = tid + i * 512;
            int p = f4 >> 4, r0 = (f4 & 15) * 4;
            float4 v = m4[f4];
            int pb = p * 64, px = p & 31;
            Ms[pb + ((r0 + 0) ^ px)] = (1.0f - v.x) * -1e9f;
            Ms[pb + ((r0 + 1) ^ px)] = (1.0f - v.y) * -1e9f;
            Ms[pb + ((r0 + 2) ^ px)] = (1.0f - v.z) * -1e9f;
            Ms[pb + ((r0 + 3) ^ px)] = (1.0f - v.w) * -1e9f;
        }
    }
    __syncthreads();

    const int e0 = w * 64;

    f32x4 acc[4][4];
#pragma unroll
    for (int mt = 0; mt < 4; ++mt)
#pragma unroll
        for (int nt = 0; nt < 4; ++nt)
            acc[mt][nt] = f32x4{0.f, 0.f, 0.f, 0.f};

    const u16* wqR0 = wq + ((size_t)(e0 + 0 * 16 + lo16)) * 512;
    const u16* wqR1 = wq + ((size_t)(e0 + 1 * 16 + lo16)) * 512;
    const u16* wqR2 = wq + ((size_t)(e0 + 2 * 16 + lo16)) * 512;
    const u16* wqR3 = wq + ((size_t)(e0 + 3 * 16 + lo16)) * 512;
    bf16x8 nb0 = *(const bf16x8*)&wqR0[8 * g];
    bf16x8 nb1 = *(const bf16x8*)&wqR1[8 * g];
    bf16x8 nb2 = *(const bf16x8*)&wqR2[8 * g];
    bf16x8 nb3 = *(const bf16x8*)&wqR3[8 * g];

#pragma unroll
    for (int ks = 0; ks < 16; ++ks) {
        const int kc = ks * 32 + 8 * g;
        bf16x8 cb0 = nb0, cb1 = nb1, cb2 = nb2, cb3 = nb3;
        if (ks < 15) {
            const int kn = kc + 32;
            nb0 = *(const bf16x8*)&wqR0[kn];
            nb1 = *(const bf16x8*)&wqR1[kn];
            nb2 = *(const bf16x8*)&wqR2[kn];
            nb3 = *(const bf16x8*)&wqR3[kn];
        }
        bf16x8 a[4];
#pragma unroll
        for (int mt = 0; mt < 4; ++mt)
            a[mt] = *(const bf16x8*)(regA + (mt * 16 + lo16) * 1024 + ((kc * 2) ^ xr));
#pragma unroll
        for (int mt = 0; mt < 4; ++mt) {
            acc[mt][0] = MFMA16(a[mt], cb0, acc[mt][0]);
            acc[mt][1] = MFMA16(a[mt], cb1, acc[mt][1]);
            acc[mt][2] = MFMA16(a[mt], cb2, acc[mt][2]);
            acc[mt][3] = MFMA16(a[mt], cb3, acc[mt][3]);
        }
    }

    const u16* KtH = kt + ((size_t)(b * 8 + w)) * 4096;
    bf16x8 ak[4][2];
#pragma unroll
    for (int ks2 = 0; ks2 < 2; ++ks2)
#pragma unroll
        for (int mt = 0; mt < 4; ++mt)
            ak[mt][ks2] = *(const bf16x8*)&KtH[(mt * 16 + lo16) * 64 + ks2 * 32 + 8 * g];

#pragma unroll
    for (int nt = 0; nt < 4; ++nt) {
        const float bq = in_b[e0 + nt * 16 + lo16];
#pragma unroll
        for (int mt = 0; mt < 4; ++mt)
#pragma unroll
            for (int i = 0; i < 4; ++i)
                acc[mt][nt][i] += bq;
    }
    __syncthreads();

    char* Qw = regA + w * 8192;
#pragma unroll
    for (int mt = 0; mt < 4; ++mt)
#pragma unroll
        for (int nt = 0; nt < 4; ++nt)
#pragma unroll
            for (int i = 0; i < 4; ++i) {
                const int p = mt * 16 + 4 * g + i;
                const int d = nt * 16 + lo16;
                *(u16*)(Qw + p * 128 + ((d * 2) ^ ((p & 7) << 4))) = f2bf(acc[mt][nt][i]);
            }

    f32x4 s[4][4];
#pragma unroll
    for (int mt = 0; mt < 4; ++mt)
#pragma unroll
        for (int nt = 0; nt < 4; ++nt)
            s[mt][nt] = f32x4{0.f, 0.f, 0.f, 0.f};

#pragma unroll
    for (int ks2 = 0; ks2 < 2; ++ks2) {
        const int kcb = (ks2 * 32 + 8 * g) * 2;
        bf16x8 bq_[4];
#pragma unroll
        for (int nt = 0; nt < 4; ++nt)
            bq_[nt] = *(const bf16x8*)(Qw + (nt * 16 + lo16) * 128 + (kcb ^ xr));
#pragma unroll
        for (int mt = 0; mt < 4; ++mt)
#pragma unroll
            for (int nt = 0; nt < 4; ++nt)
                s[mt][nt] = MFMA16(ak[mt][ks2], bq_[nt], s[mt][nt]);
    }

    const u16* VtH = vt + ((size_t)(b * 8 + w)) * 4096;
    bf16x8 av[4][2];
#pragma unroll
    for (int ks2 = 0; ks2 < 2; ++ks2)
#pragma unroll
        for (int mt = 0; mt < 4; ++mt)
            av[mt][ks2] = *(const bf16x8*)&VtH[(mt * 16 + lo16) * 64 + ks2 * 32 + 8 * g];

#pragma unroll
    for (int nt = 0; nt < 4; ++nt) {
        const int p = nt * 16 + lo16;
        const int pb = p * 64, px = p & 31;
        float mx = -3.4e38f;
#pragma unroll
        for (int mt = 0; mt < 4; ++mt)
#pragma unroll
            for (int i = 0; i < 4; ++i) {
                float v = s[mt][nt][i] * 0.125f + Ms[pb + ((mt * 16 + 4 * g + i) ^ px)];
                s[mt][nt][i] = v;
                mx = fmaxf(mx, v);
            }
        mx = fmaxf(mx, __shfl_xor(mx, 16));
        mx = fmaxf(mx, __shfl_xor(mx, 32));
        float sum = 0.f;
#pragma unroll
        for (int mt = 0; mt < 4; ++mt)
#pragma unroll
            for (int i = 0; i < 4; ++i) {
                float ev = __expf(s[mt][nt][i] - mx);
                s[mt][nt][i] = ev;
                sum += ev;
            }
        sum += __shfl_xor(sum, 16);
        sum += __shfl_xor(sum, 32);
        const float inv = 1.0f / sum;
#pragma unroll
        for (int mt = 0; mt < 4; ++mt)
#pragma unroll
            for (int i = 0; i < 4; ++i) {
                const int r = mt * 16 + 4 * g + i;
                *(u16*)(Qw + p * 128 + ((r * 2) ^ ((p & 7) << 4))) = f2bf(s[mt][nt][i] * inv);
            }
    }

    f32x4 c_[4][4];
#pragma unroll
    for (int mt = 0; mt < 4; ++mt)
#pragma unroll
        for (int nt = 0; nt < 4; ++nt)
            c_[mt][nt] = f32x4{0.f, 0.f, 0.f, 0.f};

#pragma unroll
    for (int ks2 = 0; ks2 < 2; ++ks2) {
        const int kcb = (ks2 * 32 + 8 * g) * 2;
        bf16x8 bs_[4];
#pragma unroll
        for (int nt = 0; nt < 4; ++nt)
            bs_[nt] = *(const bf16x8*)(Qw + (nt * 16 + lo16) * 128 + (kcb ^ xr));
#pragma unroll
        for (int mt = 0; mt < 4; ++mt)
#pragma unroll
            for (int nt = 0; nt < 4; ++nt)
                c_[mt][nt] = MFMA16(av[mt][ks2], bs_[nt], c_[mt][nt]);
    }
    __syncthreads();

#pragma unroll
    for (int mt = 0; mt < 4; ++mt)
#pragma unroll
        for (int nt = 0; nt < 4; ++nt)
#pragma unroll
            for (int i = 0; i < 4; ++i) {
                const int p = nt * 16 + lo16;
                const int c = e0 + mt * 16 + 4 * g + i;
                *(u16*)(regA + p * 1024 + ((c * 2) ^ ((p & 7) << 4))) = f2bf(c_[mt][nt][i]);
            }
    __syncthreads();

    f32x4 o_[4][4];
#pragma unroll
    for (int mt = 0; mt < 4; ++mt)
#pragma unroll
        for (int nt = 0; nt < 4; ++nt)
            o_[mt][nt] = f32x4{0.f, 0.f, 0.f, 0.f};

    const u16* woR0 = wo + ((size_t)(e0 + 0 * 16 + lo16)) * 512;
    const u16* woR1 = wo + ((size_t)(e0 + 1 * 16 + lo16)) * 512;
    const u16* woR2 = wo + ((size_t)(e0 + 2 * 16 + lo16)) * 512;
    const u16* woR3 = wo + ((size_t)(e0 + 3 * 16 + lo16)) * 512;
    bf16x8 ob0 = *(const bf16x8*)&woR0[8 * g];
    bf16x8 ob1 = *(const bf16x8*)&woR1[8 * g];
    bf16x8 ob2 = *(const bf16x8*)&woR2[8 * g];
    bf16x8 ob3 = *(const bf16x8*)&woR3[8 * g];

#pragma unroll
    for (int ks = 0; ks < 16; ++ks) {
        const int kc = ks * 32 + 8 * g;
        bf16x8 cb0 = ob0, cb1 = ob1, cb2 = ob2, cb3 = ob3;
        if (ks < 15) {
            const int kn = kc + 32;
            ob0 = *(const bf16x8*)&woR0[kn];
            ob1 = *(const bf16x8*)&woR1[kn];
            ob2 = *(const bf16x8*)&woR2[kn];
            ob3 = *(const bf16x8*)&woR3[kn];
        }
        bf16x8 a[4];
#pragma unroll
        for (int mt = 0; mt < 4; ++mt)
            a[mt] = *(const bf16x8*)(regA + (mt * 16 + lo16) * 1024 + ((kc * 2) ^ xr));
#pragma unroll
        for (int mt = 0; mt < 4; ++mt) {
            o_[mt][0] = MFMA16(a[mt], cb0, o_[mt][0]);
            o_[mt][1] = MFMA16(a[mt], cb1, o_[mt][1]);
            o_[mt][2] = MFMA16(a[mt], cb2, o_[mt][2]);
            o_[mt][3] = MFMA16(a[mt], cb3, o_[mt][3]);
        }
    }

#pragma unroll
    for (int nt = 0; nt < 4; ++nt) {
        const int e = e0 + nt * 16 + lo16;
        const float bo = out_b[e];
#pragma unroll
        for (int mt = 0; mt < 4; ++mt)
#pragma unroll
            for (int i = 0; i < 4; ++i) {
                const int p = mt * 16 + 4 * g + i;
                const size_t gid = vbase + (size_t)p * 512 + e;
                out[gid] = o_[mt][nt][i] + bo + visual[gid];
            }
    }
}

extern "C" void kernel_launch(void* const* d_in, const int* in_sizes, int n_in,
                              void* d_out, int out_size, void* d_ws, size_t ws_size,
                              hipStream_t stream) {
    const float* visual = (const float*)d_in[0];
    const float* region = (const float*)d_in[1];
    const float* mask   = (const float*)d_in[2];
    const float* in_w   = (const float*)d_in[3];
    const float* in_b   = (const float*)d_in[4];
    const float* out_w  = (const float*)d_in[5];
    const float* out_b  = (const float*)d_in[6];
    float* out = (float*)d_out;

    char* ws = (char*)d_ws;
    u16* wq = (u16*)(ws + 0);          // 512 KB
    u16* wo = (u16*)(ws + 524288);     // 512 KB
    u16* kt = (u16*)(ws + 1048576);    // 2 MB  [b][h][r][d]
    u16* vt = (u16*)(ws + 3145728);    // 2 MB  [b][h][d][r]
    u16* cbp = (u16*)(ws + 5242880);   // 128 MiB [b][h][p][d]
    const size_t REQ = 5242880ull + 134217728ull;

    frgca_prep<<<dim3(160), dim3(256), 0, stream>>>(region, in_w, in_b, out_w, wq, wo, kt, vt);

    if (ws_size >= REQ) {
        frgca_qattn<<<dim3(64, 32), dim3(512), 0, stream>>>(visual, mask, in_b, wq, kt, vt, cbp);
        frgca_oproj5<<<dim3(1024, 2), dim3(512), 0, stream>>>(cbp, wo, out_b, visual, out);
    } else {
        frgca_main<<<dim3(64, 32), dim3(512), 0, stream>>>(visual, mask, in_b, out_b, wq, wo, kt, vt, out);
    }
}